// Round 3
// baseline (405.410 us; speedup 1.0000x reference)
//
#include <hip/hip_runtime.h>
#include <hip/hip_cooperative_groups.h>
#include <hip/hip_bf16.h>
#include <stdint.h>

namespace cg = cooperative_groups;

// Problem constants (fixed by reference spec; dtypes f32/int32 verified over
// rounds 3-15 — bit-stable outputs; bounds-clamps retained as the safety net)
#define N_NODES   10000
#define D_FEAT    256
#define E_EDGES   320000
#define ROW_WORDS 313     // ceil(10000/32) bitmap words per row
#define LIST_CAP  1024    // per-wave neighbor list capacity (max deg ~100)

// Tier-2 (r16-proven, 132 us) fine-bucket CSR constants
#define NB     1000       // buckets
#define RPB    10         // rows per bucket
#define B_CAP  1024       // entries per bucket; mean 640, sigma ~25 (15+ sigma)
#define NBLK_E 313        // edge blocks ((320000+1023)/1024)
#define NBLK_W 64         // wcast blocks appended
#define NBLK_C 1000       // csr blocks in csr_gemm (1:1 with buckets)
#define NBLK_G 625        // gemm blocks (16 rows each)
#define COLSTR 128        // fixed col entries per row

#define LDSTR 264         // f16 LDS row stride for gemm (256 + 8 pad)
#define GRID_C 1024       // coop grid: 4 blocks/CU x 256 CUs, co-resident

typedef __attribute__((ext_vector_type(4))) float float4v;   // 4 x f32
typedef _Float16 half8  __attribute__((ext_vector_type(8))); // 8 x f16 (4 VGPR)
typedef _Float16 half4v __attribute__((ext_vector_type(4))); // 4 x f16

__device__ __forceinline__ float h2f_lo(uint32_t u) {
    union { uint32_t u; _Float16 h[2]; } v; v.u = u; return (float)v.h[0];
}
__device__ __forceinline__ float h2f_hi(uint32_t u) {
    union { uint32_t u; _Float16 h[2]; } v; v.u = u; return (float)v.h[1];
}

// ===========================================================================
// TIER-1 PLAN (r19): ONE cooperative kernel, 2 grid syncs.
// r18 post-mortem: two structurally different 4-dispatch plans land at
// 132/140 us while summed phase work models at ~50-60 us — the invariant is
// the dispatch structure (full drain + ramp per boundary, zero overlap).
// This kernel fuses everything:
//   P0: wcast (blocks 0..63) || edge scatter (all blocks, grid-stride)
//   -- grid.sync --
//   P1: yw = f16(x@W) MFMA (blocks 0..624) || popc->dinv (all blocks)
//   -- grid.sync --
//   P2: bitmap -> LDS list expand -> 8-stream f16 yw gather -> out
// Guarded: if hipLaunchCooperativeKernel errors, fall through to the
// r16-proven tier-2 3-dispatch path (132 us).
// ===========================================================================
__global__ void __launch_bounds__(256, 4)
fused_gcn(const int* __restrict__ ei, uint32_t* __restrict__ bitmap,
          const float* __restrict__ w, _Float16* __restrict__ wt,
          const float* __restrict__ x, float* __restrict__ dinv,
          _Float16* __restrict__ yw, float* __restrict__ out) {
    cg::grid_group grid = cg::this_grid();
    __shared__ __align__(16) uint8_t smem[16384];   // lists 16KB / a_lds 8.4KB / wstage 4KB
    int t = threadIdx.x;
    int bid = blockIdx.x;
    int wv = t >> 6, lane = t & 63;

    // ---- P0a: wcast (blocks 0..63): wt[n][k] = f16(W[k][n]) ----
    if (bid < 64) {
        float* st = (float*)smem;                  // 4 KB staging
        int kb = bid * 4;
        for (int idx = t; idx < 1024; idx += 256)  // contiguous 4 rows of W
            st[idx] = w[(size_t)kb * D_FEAT + idx];
        __syncthreads();
        int n = t;                                 // bank-safe: stride-256 words
        half4v o = { (_Float16)st[0 * 256 + n], (_Float16)st[1 * 256 + n],
                     (_Float16)st[2 * 256 + n], (_Float16)st[3 * 256 + n] };
        *(half4v*)&wt[(size_t)n * D_FEAT + kb] = o;
    }
    // ---- P0b: edge scatter (all blocks, grid-stride, 2 atomicOr/edge) ----
    for (int e = bid * 256 + t; e < E_EDGES; e += GRID_C * 256) {
        int s = ei[e], d = ei[E_EDGES + e];
        if ((uint32_t)s < N_NODES && (uint32_t)d < N_NODES) {
            atomicOr(&bitmap[(size_t)s * ROW_WORDS + (d >> 5)], 1u << (d & 31));
            atomicOr(&bitmap[(size_t)d * ROW_WORDS + (s >> 5)], 1u << (s & 31));
        }
    }
    grid.sync();

    // ---- P1a: gemm (blocks 0..624): yw[16 rows] = f16(x @ W) ----
    if (bid < NBLK_G) {
        _Float16* a_lds = (_Float16*)smem;         // 16*264 f16 = 8448 B
        int r0 = bid * 16;
        for (int idx = t; idx < 1024; idx += 256) {
            int row = idx >> 6, c4 = (idx & 63) * 4;
            float4v xv = *(const float4v*)(x + (size_t)(r0 + row) * D_FEAT + c4);
            half4v h = { (_Float16)xv[0], (_Float16)xv[1],
                         (_Float16)xv[2], (_Float16)xv[3] };
            *(half4v*)&a_lds[row * LDSTR + c4] = h;
        }
        __syncthreads();
        int quad = lane >> 4, r = lane & 15;
        for (int s = 0; s < 4; s++) {              // 4 waves x 4 col-tiles = 16
            int ct = wv * 4 + s;
            const _Float16* pb = wt + (size_t)(ct * 16 + r) * D_FEAT + quad * 8;
            float4v acc = {0.f, 0.f, 0.f, 0.f};
            #pragma unroll
            for (int kk = 0; kk < D_FEAT; kk += 32) {
                half8 a = *(const half8*)&a_lds[r * LDSTR + kk + quad * 8];
                half8 b = *(const half8*)(pb + kk);
                acc = __builtin_amdgcn_mfma_f32_16x16x32_f16(a, b, acc, 0, 0, 0);
            }
            int colg = ct * 16 + r;
            #pragma unroll
            for (int u = 0; u < 4; u++)
                yw[(size_t)(r0 + quad * 4 + u) * D_FEAT + colg] = (_Float16)acc[u];
        }
    }
    // ---- P1b: popc -> dinv (all blocks, wave-per-row grid-stride) ----
    for (int i = bid * 4 + wv; i < N_NODES; i += GRID_C * 4) {
        const uint32_t* rb = bitmap + (size_t)i * ROW_WORDS;
        int pop = 0;
        #pragma unroll
        for (int k = 0; k < 5; k++) {
            int ww = lane + 64 * k;
            if (ww < ROW_WORDS) pop += __popc(rb[ww]);
        }
        #pragma unroll
        for (int off = 32; off > 0; off >>= 1) pop += __shfl_xor(pop, off, 64);
        if (lane == 0) dinv[i] = 1.0f / sqrtf((float)(pop + 1));  // +1 = eye
    }
    grid.sync();

    // ---- P2: gather (wave-per-row, r7-proven expand + r13-proven streams) --
    const uint16_t* ywu = (const uint16_t*)yw;
    uint32_t* list = (uint32_t*)smem + (size_t)wv * LIST_CAP;
    for (int i = bid * 4 + wv; i < N_NODES; i += GRID_C * 4) {
        const uint32_t* rb = bitmap + (size_t)i * ROW_WORDS;
        uint32_t wbits[5]; int tot = 0;
        #pragma unroll
        for (int k = 0; k < 5; k++) {
            int ww = lane + 64 * k;
            uint32_t b = (ww < ROW_WORDS) ? rb[ww] : 0u;
            wbits[k] = b;
            tot += __popc(b);
        }
        int incl = tot;
        #pragma unroll
        for (int off = 1; off < 64; off <<= 1) {
            int v = __shfl_up(incl, off, 64);
            if (lane >= off) incl += v;
        }
        uint32_t p = (uint32_t)(incl - tot);
        uint32_t deg = (uint32_t)__shfl(incl, 63, 64);
        #pragma unroll
        for (int k = 0; k < 5; k++) {
            uint32_t bits = wbits[k];
            uint32_t cbase = (uint32_t)(lane + 64 * k) << 5;
            while (bits) {
                if (p < LIST_CAP) list[p] = cbase + (uint32_t)__builtin_ctz(bits);
                p++;
                bits &= bits - 1;
            }
        }
        if (deg > LIST_CAP) deg = LIST_CAP;
        // per-wave LDS, same-wave visibility (compiler lgkmcnt) — no barrier

        float di = dinv[i];
        size_t ch = (size_t)lane * 4;             // u16 elem offset within row
        float4v z = {0.f, 0.f, 0.f, 0.f};
        float4v a0 = z, a1 = z, a2 = z, a3 = z, a4 = z, a5 = z, a6 = z, a7 = z;
        uint32_t t8 = deg & ~7u;
        uint32_t tt = 0;
        for (; tt < t8; tt += 8) {
            uint4 jv0 = *(const uint4*)&list[tt];
            uint4 jv1 = *(const uint4*)&list[tt + 4];
            uint32_t j0 = jv0.x, j1 = jv0.y, j2 = jv0.z, j3 = jv0.w;
            uint32_t j4 = jv1.x, j5 = jv1.y, j6 = jv1.z, j7 = jv1.w;
            float d0 = dinv[j0], d1 = dinv[j1], d2 = dinv[j2], d3 = dinv[j3];
            float d4 = dinv[j4], d5 = dinv[j5], d6 = dinv[j6], d7 = dinv[j7];
            uint2 g0 = *(const uint2*)(ywu + (size_t)j0 * D_FEAT + ch);
            uint2 g1 = *(const uint2*)(ywu + (size_t)j1 * D_FEAT + ch);
            uint2 g2 = *(const uint2*)(ywu + (size_t)j2 * D_FEAT + ch);
            uint2 g3 = *(const uint2*)(ywu + (size_t)j3 * D_FEAT + ch);
            uint2 g4 = *(const uint2*)(ywu + (size_t)j4 * D_FEAT + ch);
            uint2 g5 = *(const uint2*)(ywu + (size_t)j5 * D_FEAT + ch);
            uint2 g6 = *(const uint2*)(ywu + (size_t)j6 * D_FEAT + ch);
            uint2 g7 = *(const uint2*)(ywu + (size_t)j7 * D_FEAT + ch);
            a0[0] += d0 * h2f_lo(g0.x); a0[1] += d0 * h2f_hi(g0.x);
            a0[2] += d0 * h2f_lo(g0.y); a0[3] += d0 * h2f_hi(g0.y);
            a1[0] += d1 * h2f_lo(g1.x); a1[1] += d1 * h2f_hi(g1.x);
            a1[2] += d1 * h2f_lo(g1.y); a1[3] += d1 * h2f_hi(g1.y);
            a2[0] += d2 * h2f_lo(g2.x); a2[1] += d2 * h2f_hi(g2.x);
            a2[2] += d2 * h2f_lo(g2.y); a2[3] += d2 * h2f_hi(g2.y);
            a3[0] += d3 * h2f_lo(g3.x); a3[1] += d3 * h2f_hi(g3.x);
            a3[2] += d3 * h2f_lo(g3.y); a3[3] += d3 * h2f_hi(g3.y);
            a4[0] += d4 * h2f_lo(g4.x); a4[1] += d4 * h2f_hi(g4.x);
            a4[2] += d4 * h2f_lo(g4.y); a4[3] += d4 * h2f_hi(g4.y);
            a5[0] += d5 * h2f_lo(g5.x); a5[1] += d5 * h2f_hi(g5.x);
            a5[2] += d5 * h2f_lo(g5.y); a5[3] += d5 * h2f_hi(g5.y);
            a6[0] += d6 * h2f_lo(g6.x); a6[1] += d6 * h2f_hi(g6.x);
            a6[2] += d6 * h2f_lo(g6.y); a6[3] += d6 * h2f_hi(g6.y);
            a7[0] += d7 * h2f_lo(g7.x); a7[1] += d7 * h2f_hi(g7.x);
            a7[2] += d7 * h2f_lo(g7.y); a7[3] += d7 * h2f_hi(g7.y);
        }
        for (; tt < deg; tt++) {
            uint32_t j = list[tt];
            float dj = dinv[j];
            uint2 g = *(const uint2*)(ywu + (size_t)j * D_FEAT + ch);
            a0[0] += dj * h2f_lo(g.x); a0[1] += dj * h2f_hi(g.x);
            a0[2] += dj * h2f_lo(g.y); a0[3] += dj * h2f_hi(g.y);
        }
        uint2 gs = *(const uint2*)(ywu + (size_t)i * D_FEAT + ch); // +I self
        a1[0] += di * h2f_lo(gs.x); a1[1] += di * h2f_hi(gs.x);
        a1[2] += di * h2f_lo(gs.y); a1[3] += di * h2f_hi(gs.y);
        float4v acc = ((a0 + a1) + (a2 + a3)) + ((a4 + a5) + (a6 + a7));
        *(float4v*)(out + (size_t)i * D_FEAT + ch) = di * acc;
    }
}

// ===========================================================================
// TIER-2 PLAN (r16/r17-proven, 132 us, 12.0 MB) — used when ws < 17.8 MB or
// cooperative launch is rejected.
// ===========================================================================

__global__ void __launch_bounds__(1024)
fill_sort(const int* __restrict__ ei, uint32_t* __restrict__ bucketbuf,
          uint32_t* __restrict__ cursors,
          const float* __restrict__ w, _Float16* __restrict__ wt) {
    __shared__ uint32_t hist[1024];
    __shared__ uint32_t lofs[1024];    // inclusive scan of hist
    __shared__ uint32_t base_s[1024];
    __shared__ uint32_t wsum[16];      // per-wave partial sums
    __shared__ uint32_t stage[2048];   // also reused as f32[1024] by wcast
    __shared__ uint16_t sbkt[2048];
    int t = threadIdx.x;

    if (blockIdx.x >= NBLK_E) {        // ---- fused wcast blocks ----
        int kb = (blockIdx.x - NBLK_E) * 4;
        int k = kb + (t >> 8), n = t & 255;
        float* st = (float*)stage;     // 4 KB staging
        st[(n << 2) | (t >> 8)] = w[(size_t)k * D_FEAT + n];
        __syncthreads();
        if (t < 256) {
            half4v o = { (_Float16)st[t * 4 + 0], (_Float16)st[t * 4 + 1],
                         (_Float16)st[t * 4 + 2], (_Float16)st[t * 4 + 3] };
            *(half4v*)&wt[(size_t)t * D_FEAT + kb] = o;
        }
        return;
    }

    int wv = t >> 6, lane = t & 63;
    hist[t] = 0;
    __syncthreads();
    int e = blockIdx.x * 1024 + t;
    int b0 = -1, b1 = -1; uint32_t ent0 = 0, ent1 = 0, s0 = 0, s1 = 0;
    if (e < E_EDGES) {
        int s = ei[e], d = ei[E_EDGES + e];
        if ((uint32_t)s < N_NODES && (uint32_t)d < N_NODES) {
            b0 = s / RPB; ent0 = ((uint32_t)(s - b0 * RPB) << 14) | (uint32_t)d;
            b1 = d / RPB; ent1 = ((uint32_t)(d - b1 * RPB) << 14) | (uint32_t)s;
            s0 = atomicAdd(&hist[b0], 1u);    // LDS atomics
            s1 = atomicAdd(&hist[b1], 1u);
        }
    }
    __syncthreads();
    uint32_t h = hist[t];
    uint32_t incl = h;
    #pragma unroll
    for (int off = 1; off < 64; off <<= 1) {
        uint32_t v = __shfl_up(incl, off, 64);
        if (lane >= off) incl += v;
    }
    if (lane == 63) wsum[wv] = incl;
    __syncthreads();
    if (wv == 0) {
        uint32_t s = (lane < 16) ? wsum[lane] : 0u;
        #pragma unroll
        for (int off = 1; off < 16; off <<= 1) {
            uint32_t v = __shfl_up(s, off, 64);
            if (lane >= off) s += v;
        }
        if (lane < 16) wsum[lane] = s;
    }
    __syncthreads();
    uint32_t wbase = wv ? wsum[wv - 1] : 0u;
    lofs[t] = incl + wbase;                          // inclusive scan value
    base_s[t] = h ? atomicAdd(&cursors[t], h) : 0u;
    __syncthreads();
    if (b0 >= 0) {                     // stage sorted by bucket
        uint32_t p0 = lofs[b0] - hist[b0] + s0;
        stage[p0] = ent0; sbkt[p0] = (uint16_t)b0;
        uint32_t p1 = lofs[b1] - hist[b1] + s1;
        stage[p1] = ent1; sbkt[p1] = (uint16_t)b1;
    }
    __syncthreads();
    uint32_t total = lofs[1023];
    for (uint32_t idx = t; idx < total; idx += 1024) {
        uint32_t b = sbkt[idx];
        uint32_t pos = base_s[b] + (idx - (lofs[b] - hist[b]));
        if (pos < B_CAP) bucketbuf[(size_t)b * B_CAP + pos] = stage[idx];
    }
}

__global__ void __launch_bounds__(1024)
csr_gemm(const uint32_t* __restrict__ bucketbuf, const uint32_t* __restrict__ cursors,
         uint32_t* __restrict__ row_deg, float* __restrict__ dinv,
         uint16_t* __restrict__ col,
         const float* __restrict__ x, const _Float16* __restrict__ wt,
         _Float16* __restrict__ yw) {
    __shared__ __align__(16) uint32_t smem[RPB * ROW_WORDS];   // 12,520 B
    int t = threadIdx.x;

    if (blockIdx.x >= NBLK_C) {        // ---- gemm blocks ----
        _Float16* a_lds = (_Float16*)smem;             // 16*264 f16 = 8448 B
        int r0 = (blockIdx.x - NBLK_C) * 16;
        int row = t >> 6, c4 = (t & 63) * 4;           // 1024 thr = 16x64 f4
        float4v xv = *(const float4v*)(x + (size_t)(r0 + row) * D_FEAT + c4);
        half4v h = { (_Float16)xv[0], (_Float16)xv[1],
                     (_Float16)xv[2], (_Float16)xv[3] };
        *(half4v*)&a_lds[row * LDSTR + c4] = h;
        __syncthreads();
        int wv = t >> 6, lane = t & 63;
        int quad = lane >> 4, r = lane & 15;
        int ct = wv;                                   // 16 waves = 16 col tiles
        const _Float16* pb = wt + (size_t)(ct * 16 + r) * D_FEAT + quad * 8;
        float4v acc = {0.f, 0.f, 0.f, 0.f};
        #pragma unroll
        for (int kk = 0; kk < D_FEAT; kk += 32) {
            half8 a = *(const half8*)&a_lds[r * LDSTR + kk + quad * 8];
            half8 b = *(const half8*)(pb + kk);
            acc = __builtin_amdgcn_mfma_f32_16x16x32_f16(a, b, acc, 0, 0, 0);
        }
        int colg = ct * 16 + r;
        #pragma unroll
        for (int u = 0; u < 4; u++)
            yw[(size_t)(r0 + quad * 4 + u) * D_FEAT + colg] = (_Float16)acc[u];
        return;
    }

    // ---- csr blocks (1:1 with buckets) ----
    uint32_t* bm = smem;                               // 10*313 words
    int b = blockIdx.x;
    for (int i = t; i < RPB * ROW_WORDS; i += 1024) bm[i] = 0;
    __syncthreads();
    uint32_t cnt = min(cursors[b], (uint32_t)B_CAP);
    const uint32_t* bb = bucketbuf + (size_t)b * B_CAP;
    for (uint32_t i = t; i < cnt; i += 1024) {         // <= 1 iteration
        uint32_t ent = bb[i];
        uint32_t lr = ent >> 14, d = ent & 0x3FFFu;
        atomicOr(&bm[lr * ROW_WORDS + (d >> 5)], 1u << (d & 31));
    }
    __syncthreads();
    int wv = t >> 6, lane = t & 63;                    // 16 waves, 10 rows
    if (wv < RPB) {
        int r = wv;
        int gi = b * RPB + r;
        uint32_t wb[5]; int tot = 0;
        #pragma unroll
        for (int k = 0; k < 5; k++) {
            int w = lane + 64 * k;
            uint32_t v = (w < ROW_WORDS) ? bm[r * ROW_WORDS + w] : 0u;
            wb[k] = v; tot += __popc(v);
        }
        int incl = tot;
        #pragma unroll
        for (int off = 1; off < 64; off <<= 1) {
            int v = __shfl_up(incl, off, 64);
            if (lane >= off) incl += v;
        }
        uint32_t total = (uint32_t)__shfl(incl, 63, 64);
        if (lane == 0) {
            row_deg[gi] = min(total, (uint32_t)COLSTR);
            dinv[gi]    = 1.0f / sqrtf((float)(total + 1u));  // +1 = the eye
        }
        uint32_t p = (uint32_t)(incl - tot);
        #pragma unroll
        for (int k = 0; k < 5; k++) {
            uint32_t bits = wb[k];
            uint32_t cbase = (uint32_t)(lane + 64 * k) << 5;
            while (bits) {
                if (p < COLSTR)
                    col[(size_t)gi * COLSTR + p] =
                        (uint16_t)(cbase + (uint32_t)__builtin_ctz(bits));
                p++;
                bits &= bits - 1;
            }
        }
    }
}

__global__ void __launch_bounds__(256)
spmm_out(const uint32_t* __restrict__ row_deg, const float* __restrict__ dinv,
         const uint16_t* __restrict__ col, const _Float16* __restrict__ ywp,
         float* __restrict__ out) {
    const uint16_t* yw = (const uint16_t*)ywp;
    int wv = threadIdx.x >> 6, lane = threadIdx.x & 63;
    int half = lane >> 5, sl = lane & 31;
    int i = blockIdx.x * 4 + wv;
    uint32_t base = (uint32_t)i * COLSTR;
    uint32_t deg = min(row_deg[i], (uint32_t)COLSTR);
    float di = dinv[i];
    size_t ch = (size_t)sl * 8;                 // u16 elem offset within row
    float4v z = {0.f, 0.f, 0.f, 0.f};
    float4v accl[8], acch[8];
    #pragma unroll
    for (int k = 0; k < 8; k++) { accl[k] = z; acch[k] = z; }

    uint32_t hb = (uint32_t)(half << 3);
    uint4 cv = {0u, 0u, 0u, 0u};
    if (deg) cv = *(const uint4*)&col[base + hb];     // 8 idx, half-uniform

    for (uint32_t t = 0; t < deg; t += 16) {
        uint4 cvn = {0u, 0u, 0u, 0u};                 // prefetch next col blk
        uint32_t tn = t + 16;
        if (tn < deg) cvn = *(const uint4*)&col[base + tn + hb];
        uint32_t tb = t + hb;
        uint32_t jr[8];
        jr[0] = cv.x & 0xffffu; jr[1] = cv.x >> 16;
        jr[2] = cv.y & 0xffffu; jr[3] = cv.y >> 16;
        jr[4] = cv.z & 0xffffu; jr[5] = cv.z >> 16;
        jr[6] = cv.w & 0xffffu; jr[7] = cv.w >> 16;
        uint4 g[8]; float dk[8];
        #pragma unroll
        for (int k = 0; k < 8; k++) {                 // issue all 16 loads
            uint32_t j = min(jr[k], (uint32_t)(N_NODES - 1));  // stay in-bounds
            g[k]  = *(const uint4*)(yw + ((size_t)j << 8) + ch);
            dk[k] = dinv[j];
        }
        #pragma unroll
        for (int k = 0; k < 8; k++) {                 // convert + accumulate
            float d = (tb + (uint32_t)k < deg) ? dk[k] : 0.f;   // tail mask
            accl[k][0] += d * h2f_lo(g[k].x); accl[k][1] += d * h2f_hi(g[k].x);
            accl[k][2] += d * h2f_lo(g[k].y); accl[k][3] += d * h2f_hi(g[k].y);
            acch[k][0] += d * h2f_lo(g[k].z); acch[k][1] += d * h2f_hi(g[k].z);
            acch[k][2] += d * h2f_lo(g[k].w); acch[k][3] += d * h2f_hi(g[k].w);
        }
        cv = cvn;
    }

    if (half == 0) {                            // +I self term, once per row
        const uint4 gs = *(const uint4*)(yw + ((size_t)i << 8) + ch);
        accl[0][0] += di * h2f_lo(gs.x); accl[0][1] += di * h2f_hi(gs.x);
        accl[0][2] += di * h2f_lo(gs.y); accl[0][3] += di * h2f_hi(gs.y);
        acch[0][0] += di * h2f_lo(gs.z); acch[0][1] += di * h2f_hi(gs.z);
        acch[0][2] += di * h2f_lo(gs.w); acch[0][3] += di * h2f_hi(gs.w);
    }

    float4v lo = ((accl[0] + accl[1]) + (accl[2] + accl[3])) +
                 ((accl[4] + accl[5]) + (accl[6] + accl[7]));
    float4v hi = ((acch[0] + acch[1]) + (acch[2] + acch[3])) +
                 ((acch[4] + acch[5]) + (acch[6] + acch[7]));
    #pragma unroll
    for (int u = 0; u < 4; u++) {               // fold the two halves
        lo[u] += __shfl_xor(lo[u], 32, 64);
        hi[u] += __shfl_xor(hi[u], 32, 64);
    }
    float4v res;
    if (half) res = hi; else res = lo;
    float* op = out + (size_t)i * D_FEAT + (size_t)sl * 8 + (half ? 4 : 0);
    *(float4v*)op = di * res;
}

// ---------------------------------------------------------------------------
extern "C" void kernel_launch(void* const* d_in, const int* in_sizes, int n_in,
                              void* d_out, int out_size, void* d_ws, size_t ws_size,
                              hipStream_t stream) {
    const float* x  = (const float*)d_in[0];     // f32 [N, 256]
    const int*   ei = (const int*)d_in[1];       // int32 [2, E]
    const float* w  = (const float*)d_in[2];     // f32 [256, 256]
    float* out = (float*)d_out;                  // f32 [N, 256]
    uint8_t* ws = (uint8_t*)d_ws;

    // Tier-1 layout (17.81 MB):
    //   bitmap    @ 0          : 12,520,000  (10000 * 313 u32, memset)
    //   dinv      @ 12,520,000 :     40,000
    //   wT (f16)  @ 12,560,000 :    131,072
    //   yw (f16)  @ 12,691,072 :  5,120,000  (X @ W, gather table)
    const size_t T1_DI   = 12520000;
    const size_t T1_WT   = 12560000;
    const size_t T1_YW   = 12691072;
    const size_t NEED_T1 = 17811072;

    // Tier-2 layout (12.0 MB) — r16-proven:
    const size_t BB_OFF   = 4096;
    const size_t RD_OFF   = 4100096;
    const size_t DI_OFF   = 4140096;
    const size_t WT_OFF   = 4180096;
    const size_t YW_OFF   = 4311168;
    const size_t COL_OFF  = 9431168;
    const size_t NEED_T2  = 11991168;

    if (ws_size >= NEED_T1) {
        uint32_t* bitmap = (uint32_t*)ws;
        float*    dinv   = (float*)(ws + T1_DI);
        _Float16* wt     = (_Float16*)(ws + T1_WT);
        _Float16* yw     = (_Float16*)(ws + T1_YW);

        hipMemsetAsync(bitmap, 0, 12520000, stream);
        void* kargs[] = { (void*)&ei, (void*)&bitmap, (void*)&w, (void*)&wt,
                          (void*)&x,  (void*)&dinv,   (void*)&yw, (void*)&out };
        hipError_t err = hipLaunchCooperativeKernel(
            (void*)fused_gcn, dim3(GRID_C), dim3(256), kargs, 0, stream);
        if (err == hipSuccess) return;
        (void)hipGetLastError();   // clear sticky error; fall through to T2
    }
    if (ws_size >= NEED_T2) {
        uint32_t* cursors   = (uint32_t*)ws;
        uint32_t* bucketbuf = (uint32_t*)(ws + BB_OFF);
        uint32_t* row_deg   = (uint32_t*)(ws + RD_OFF);
        float*    dinv      = (float*)(ws + DI_OFF);
        _Float16* wt        = (_Float16*)(ws + WT_OFF);
        _Float16* yw        = (_Float16*)(ws + YW_OFF);
        uint16_t* col       = (uint16_t*)(ws + COL_OFF);

        hipMemsetAsync(cursors, 0, 4096, stream);
        fill_sort<<<NBLK_E + NBLK_W, 1024, 0, stream>>>(ei, bucketbuf, cursors, w, wt);
        csr_gemm <<<NBLK_C + NBLK_G, 1024, 0, stream>>>(bucketbuf, cursors,
                                                        row_deg, dinv, col, x, wt, yw);
        spmm_out <<<N_NODES / 4, 256, 0, stream>>>(row_deg, dinv, col, yw, out);
    }
    // else: ws too small for any plan — no-op (never observed).
}

// Round 5
// 131.184 us; speedup vs baseline: 3.0904x; 3.0904x over previous
//
#include <hip/hip_runtime.h>
#include <hip/hip_bf16.h>
#include <stdint.h>

// Problem constants (fixed by reference spec; dtypes f32/int32 verified over
// rounds 3-15 — bit-stable outputs; bounds-clamps retained as the safety net)
#define N_NODES   10000
#define D_FEAT    256
#define E_EDGES   320000
#define ROW_WORDS 313     // ceil(10000/32) bitmap words per row

// Fine-bucket CSR constants (r16-proven)
#define NB     1000       // buckets
#define RPB    10         // rows per bucket
#define B_CAP  1024       // entries per bucket; mean 640, sigma ~25 (15+ sigma)
#define NBLK_E 313        // sort blocks ((320000+1023)/1024)
#define NBLK_G 625        // gemm blocks (16 rows each), co-scheduled with sort
#define NBLK_C 1000       // csr blocks (1:1 with buckets)
#define COLSTR 128        // fixed col entries per row (max deg ~100 << 128)

#define LDSTR 264         // f16 LDS row stride for gemm (256 + 8 pad)

typedef __attribute__((ext_vector_type(4))) float float4v;   // 4 x f32
typedef _Float16 half8  __attribute__((ext_vector_type(8))); // 8 x f16 (4 VGPR)
typedef _Float16 half4v __attribute__((ext_vector_type(4))); // 4 x f16

__device__ __forceinline__ float h2f_lo(uint32_t u) {
    union { uint32_t u; _Float16 h[2]; } v; v.u = u; return (float)v.h[0];
}
__device__ __forceinline__ float h2f_hi(uint32_t u) {
    union { uint32_t u; _Float16 h[2]; } v; v.u = u; return (float)v.h[1];
}

// ===========================================================================
// r21 PLAN — Round-1-proven kernel bodies, recomposed for phase overlap:
//   D0 wcast_k  : wT[n][k] = f16(W[k][n])  (64 blocks, r12-proven body)
//   D1 sort_gemm: [0,313) counting-sort fill (r17-proven hierarchical scan)
//                 || [313,938) yw = f16(x @ W) MFMA (r10-proven body) —
//                 gemm depends only on wt (D0) + x, NOT on the sort, so it
//                 now hides under the sort instead of trailing the CSR pass.
//   D2 csr_only : 1000 bucket-scan -> LDS bitmap dedup -> col/deg/dinv
//                 (r16-proven body, gemm branch removed)
//   D3 spmm_out : r17-proven half-wave 16B gather -> d_out
// r18-r20 post-mortem: replacing the proven machinery (global bitmap /
// coop fusion / atomic CSR) regressed or failed; only composition changes
// are safe. All four bodies here are byte-equivalent to the Round-1 pass.
// ===========================================================================

// ---------------------------------------------------------------------------
// D0: wt[n][k] = f16(W[k][n]); 64 blocks x 1024 thr, 4 W-rows per block.
// ---------------------------------------------------------------------------
__global__ void __launch_bounds__(1024)
wcast_k(const float* __restrict__ w, _Float16* __restrict__ wt) {
    __shared__ float st[1024];
    int t = threadIdx.x;
    int kb = blockIdx.x * 4;
    int k = kb + (t >> 8), n = t & 255;
    st[(n << 2) | (t >> 8)] = w[(size_t)k * D_FEAT + n];
    __syncthreads();
    if (t < 256) {
        half4v o = { (_Float16)st[t * 4 + 0], (_Float16)st[t * 4 + 1],
                     (_Float16)st[t * 4 + 2], (_Float16)st[t * 4 + 3] };
        *(half4v*)&wt[(size_t)t * D_FEAT + kb] = o;
    }
}

// ---------------------------------------------------------------------------
// D1: blocks [0,313): counting-sorted fine-bucket fill (1024-bin histogram,
//     hierarchical shfl scan, coalesced run writes) — r17-proven verbatim.
//     blocks [313,938): yw[16 rows] = f16(x @ W) MFMA — r10-proven verbatim
//     (reads wt from D0 cross-dispatch; disjoint from sort data).
// LDS: one 24,640 B arena, manually laid out (sort) / reused (gemm 8448 B).
// ---------------------------------------------------------------------------
__global__ void __launch_bounds__(1024)
sort_gemm(const int* __restrict__ ei, uint32_t* __restrict__ bucketbuf,
          uint32_t* __restrict__ cursors,
          const float* __restrict__ x, const _Float16* __restrict__ wt,
          _Float16* __restrict__ yw) {
    __shared__ __align__(16) uint8_t smraw[24640];
    int t = threadIdx.x;
    int wv = t >> 6, lane = t & 63;

    if (blockIdx.x >= NBLK_E) {        // ---- gemm blocks [313, 938) ----
        _Float16* a_lds = (_Float16*)smraw;            // 16*264 f16 = 8448 B
        int r0 = (blockIdx.x - NBLK_E) * 16;
        int row = t >> 6, c4 = (t & 63) * 4;           // 1024 thr = 16x64 f4
        float4v xv = *(const float4v*)(x + (size_t)(r0 + row) * D_FEAT + c4);
        half4v h = { (_Float16)xv[0], (_Float16)xv[1],
                     (_Float16)xv[2], (_Float16)xv[3] };
        *(half4v*)&a_lds[row * LDSTR + c4] = h;
        __syncthreads();
        int quad = lane >> 4, r = lane & 15;
        int ct = wv;                                   // 16 waves = 16 col tiles
        const _Float16* pb = wt + (size_t)(ct * 16 + r) * D_FEAT + quad * 8;
        float4v acc = {0.f, 0.f, 0.f, 0.f};
        #pragma unroll
        for (int kk = 0; kk < D_FEAT; kk += 32) {
            half8 a = *(const half8*)&a_lds[r * LDSTR + kk + quad * 8];
            half8 b = *(const half8*)(pb + kk);
            acc = __builtin_amdgcn_mfma_f32_16x16x32_f16(a, b, acc, 0, 0, 0);
        }
        int colg = ct * 16 + r;
        #pragma unroll
        for (int u = 0; u < 4; u++)
            yw[(size_t)(r0 + quad * 4 + u) * D_FEAT + colg] = (_Float16)acc[u];
        return;
    }

    // ---- sort blocks [0,313) — r17-proven body, arrays aliased in arena --
    uint32_t* hist   = (uint32_t*)(smraw);             //  4096 B
    uint32_t* lofs   = (uint32_t*)(smraw + 4096);      //  4096 B
    uint32_t* base_s = (uint32_t*)(smraw + 8192);      //  4096 B
    uint32_t* wsum   = (uint32_t*)(smraw + 12288);     //    64 B
    uint32_t* stage  = (uint32_t*)(smraw + 12352);     //  8192 B
    uint16_t* sbkt   = (uint16_t*)(smraw + 20544);     //  4096 B -> 24640

    hist[t] = 0;
    __syncthreads();
    int e = blockIdx.x * 1024 + t;
    int b0 = -1, b1 = -1; uint32_t ent0 = 0, ent1 = 0, s0 = 0, s1 = 0;
    if (e < E_EDGES) {
        int s = ei[e], d = ei[E_EDGES + e];
        if ((uint32_t)s < N_NODES && (uint32_t)d < N_NODES) {
            b0 = s / RPB; ent0 = ((uint32_t)(s - b0 * RPB) << 14) | (uint32_t)d;
            b1 = d / RPB; ent1 = ((uint32_t)(d - b1 * RPB) << 14) | (uint32_t)s;
            s0 = atomicAdd(&hist[b0], 1u);    // LDS atomics
            s1 = atomicAdd(&hist[b1], 1u);
        }
    }
    __syncthreads();
    // hierarchical inclusive scan: 64-wide shfl per wave, wave 0 combines
    uint32_t h = hist[t];
    uint32_t incl = h;
    #pragma unroll
    for (int off = 1; off < 64; off <<= 1) {
        uint32_t v = __shfl_up(incl, off, 64);
        if (lane >= off) incl += v;
    }
    if (lane == 63) wsum[wv] = incl;
    __syncthreads();
    if (wv == 0) {
        uint32_t s = (lane < 16) ? wsum[lane] : 0u;
        #pragma unroll
        for (int off = 1; off < 16; off <<= 1) {
            uint32_t v = __shfl_up(s, off, 64);
            if (lane >= off) s += v;
        }
        if (lane < 16) wsum[lane] = s;
    }
    __syncthreads();
    uint32_t wbase = wv ? wsum[wv - 1] : 0u;
    lofs[t] = incl + wbase;                          // inclusive scan value
    base_s[t] = h ? atomicAdd(&cursors[t], h) : 0u;
    __syncthreads();
    if (b0 >= 0) {                     // stage sorted by bucket
        uint32_t p0 = lofs[b0] - hist[b0] + s0;
        stage[p0] = ent0; sbkt[p0] = (uint16_t)b0;
        uint32_t p1 = lofs[b1] - hist[b1] + s1;
        stage[p1] = ent1; sbkt[p1] = (uint16_t)b1;
    }
    __syncthreads();
    uint32_t total = lofs[1023];
    for (uint32_t idx = t; idx < total; idx += 1024) {
        uint32_t b = sbkt[idx];
        uint32_t pos = base_s[b] + (idx - (lofs[b] - hist[b]));
        if (pos < B_CAP) bucketbuf[(size_t)b * B_CAP + pos] = stage[idx];
    }
}

// ---------------------------------------------------------------------------
// D2: 1000 csr blocks (1:1 with buckets) — r16-proven body verbatim.
// Scan cnt[b] (~640 <= 1024: ONE strided iteration), LDS bitmap dedup
// (12.5 KB), per-row popc -> deg/dinv, expand to u16 col (fixed stride).
// ---------------------------------------------------------------------------
__global__ void __launch_bounds__(1024)
csr_only(const uint32_t* __restrict__ bucketbuf, const uint32_t* __restrict__ cursors,
         uint32_t* __restrict__ row_deg, float* __restrict__ dinv,
         uint16_t* __restrict__ col) {
    __shared__ __align__(16) uint32_t bm[RPB * ROW_WORDS];   // 12,520 B
    int t = threadIdx.x;
    int b = blockIdx.x;
    for (int i = t; i < RPB * ROW_WORDS; i += 1024) bm[i] = 0;
    __syncthreads();
    uint32_t cnt = min(cursors[b], (uint32_t)B_CAP);
    const uint32_t* bb = bucketbuf + (size_t)b * B_CAP;
    for (uint32_t i = t; i < cnt; i += 1024) {         // <= 1 iteration
        uint32_t ent = bb[i];
        uint32_t lr = ent >> 14, d = ent & 0x3FFFu;
        atomicOr(&bm[lr * ROW_WORDS + (d >> 5)], 1u << (d & 31));
    }
    __syncthreads();
    int wv = t >> 6, lane = t & 63;                    // 16 waves, 10 rows
    if (wv < RPB) {
        int r = wv;
        int gi = b * RPB + r;
        uint32_t wb[5]; int tot = 0;
        #pragma unroll
        for (int k = 0; k < 5; k++) {
            int w = lane + 64 * k;
            uint32_t v = (w < ROW_WORDS) ? bm[r * ROW_WORDS + w] : 0u;
            wb[k] = v; tot += __popc(v);
        }
        int incl = tot;
        #pragma unroll
        for (int off = 1; off < 64; off <<= 1) {
            int v = __shfl_up(incl, off, 64);
            if (lane >= off) incl += v;
        }
        uint32_t total = (uint32_t)__shfl(incl, 63, 64);
        if (lane == 0) {
            row_deg[gi] = min(total, (uint32_t)COLSTR);
            dinv[gi]    = 1.0f / sqrtf((float)(total + 1u));  // +1 = the eye
        }
        uint32_t p = (uint32_t)(incl - tot);
        #pragma unroll
        for (int k = 0; k < 5; k++) {
            uint32_t bits = wb[k];
            uint32_t cbase = (uint32_t)(lane + 64 * k) << 5;
            while (bits) {
                if (p < COLSTR)
                    col[(size_t)gi * COLSTR + p] =
                        (uint16_t)(cbase + (uint32_t)__builtin_ctz(bits));
                p++;
                bits &= bits - 1;
            }
        }
    }
}

// ---------------------------------------------------------------------------
// D3: final gather straight into d_out (f32). Wave-per-row (10000 waves).
// r17-proven verbatim: half-wave per neighbor — 32 lanes x 16B cover one
// full 512B yw row; 16 neighbors/iter; next col block prefetched; tail
// folded branchlessly (index-clamp + weight-zero). yw is UNSCALED X@W.
// ---------------------------------------------------------------------------
__global__ void __launch_bounds__(256)
spmm_out(const uint32_t* __restrict__ row_deg, const float* __restrict__ dinv,
         const uint16_t* __restrict__ col, const _Float16* __restrict__ ywp,
         float* __restrict__ out) {
    const uint16_t* yw = (const uint16_t*)ywp;
    int wv = threadIdx.x >> 6, lane = threadIdx.x & 63;
    int half = lane >> 5, sl = lane & 31;
    int i = blockIdx.x * 4 + wv;
    uint32_t base = (uint32_t)i * COLSTR;
    uint32_t deg = min(row_deg[i], (uint32_t)COLSTR);
    float di = dinv[i];
    size_t ch = (size_t)sl * 8;                 // u16 elem offset within row
    float4v z = {0.f, 0.f, 0.f, 0.f};
    float4v accl[8], acch[8];
    #pragma unroll
    for (int k = 0; k < 8; k++) { accl[k] = z; acch[k] = z; }

    uint32_t hb = (uint32_t)(half << 3);
    uint4 cv = {0u, 0u, 0u, 0u};
    if (deg) cv = *(const uint4*)&col[base + hb];     // 8 idx, half-uniform

    for (uint32_t t = 0; t < deg; t += 16) {
        uint4 cvn = {0u, 0u, 0u, 0u};                 // prefetch next col blk
        uint32_t tn = t + 16;
        if (tn < deg) cvn = *(const uint4*)&col[base + tn + hb];
        uint32_t tb = t + hb;
        uint32_t jr[8];
        jr[0] = cv.x & 0xffffu; jr[1] = cv.x >> 16;
        jr[2] = cv.y & 0xffffu; jr[3] = cv.y >> 16;
        jr[4] = cv.z & 0xffffu; jr[5] = cv.z >> 16;
        jr[6] = cv.w & 0xffffu; jr[7] = cv.w >> 16;
        uint4 g[8]; float dk[8];
        #pragma unroll
        for (int k = 0; k < 8; k++) {                 // issue all 16 loads
            uint32_t j = min(jr[k], (uint32_t)(N_NODES - 1));  // stay in-bounds
            g[k]  = *(const uint4*)(yw + ((size_t)j << 8) + ch);
            dk[k] = dinv[j];
        }
        #pragma unroll
        for (int k = 0; k < 8; k++) {                 // convert + accumulate
            float d = (tb + (uint32_t)k < deg) ? dk[k] : 0.f;   // tail mask
            accl[k][0] += d * h2f_lo(g[k].x); accl[k][1] += d * h2f_hi(g[k].x);
            accl[k][2] += d * h2f_lo(g[k].y); accl[k][3] += d * h2f_hi(g[k].y);
            acch[k][0] += d * h2f_lo(g[k].z); acch[k][1] += d * h2f_hi(g[k].z);
            acch[k][2] += d * h2f_lo(g[k].w); acch[k][3] += d * h2f_hi(g[k].w);
        }
        cv = cvn;
    }

    if (half == 0) {                            // +I self term, once per row
        const uint4 gs = *(const uint4*)(yw + ((size_t)i << 8) + ch);
        accl[0][0] += di * h2f_lo(gs.x); accl[0][1] += di * h2f_hi(gs.x);
        accl[0][2] += di * h2f_lo(gs.y); accl[0][3] += di * h2f_hi(gs.y);
        acch[0][0] += di * h2f_lo(gs.z); acch[0][1] += di * h2f_hi(gs.z);
        acch[0][2] += di * h2f_lo(gs.w); acch[0][3] += di * h2f_hi(gs.w);
    }

    float4v lo = ((accl[0] + accl[1]) + (accl[2] + accl[3])) +
                 ((accl[4] + accl[5]) + (accl[6] + accl[7]));
    float4v hi = ((acch[0] + acch[1]) + (acch[2] + acch[3])) +
                 ((acch[4] + acch[5]) + (acch[6] + acch[7]));
    #pragma unroll
    for (int u = 0; u < 4; u++) {               // fold the two halves
        lo[u] += __shfl_xor(lo[u], 32, 64);
        hi[u] += __shfl_xor(hi[u], 32, 64);
    }
    float4v res;
    if (half) res = hi; else res = lo;
    // contiguous 1KB row store: lane l<32 -> feats sl*8..+3, l>=32 -> +4..+7
    float* op = out + (size_t)i * D_FEAT + (size_t)sl * 8 + (half ? 4 : 0);
    *(float4v*)op = di * res;
}

// ---------------------------------------------------------------------------
extern "C" void kernel_launch(void* const* d_in, const int* in_sizes, int n_in,
                              void* d_out, int out_size, void* d_ws, size_t ws_size,
                              hipStream_t stream) {
    const float* x  = (const float*)d_in[0];     // f32 [N, 256]
    const int*   ei = (const int*)d_in[1];       // int32 [2, E]
    const float* w  = (const float*)d_in[2];     // f32 [256, 256]
    float* out = (float*)d_out;                  // f32 [N, 256]
    uint8_t* ws = (uint8_t*)d_ws;

    // Layout (12.0 MB) — identical to the Round-1 proven plan:
    //   cursors   @ 0          :      4,096  (1000 u32, memset 4 KB)
    //   bucketbuf @ 4,096      :  4,096,000  (1000 * 1024 u32, compact)
    //   row_deg   @ 4,100,096  :     40,000
    //   dinv      @ 4,140,096  :     40,000
    //   wT (f16)  @ 4,180,096  :    131,072
    //   yw (f16)  @ 4,311,168  :  5,120,000  (X @ W, gather table)
    //   col (u16) @ 9,431,168  :  2,560,000  (10000 * 128 u16, fixed stride)
    const size_t BB_OFF   = 4096;
    const size_t RD_OFF   = 4100096;
    const size_t DI_OFF   = 4140096;
    const size_t WT_OFF   = 4180096;
    const size_t YW_OFF   = 4311168;
    const size_t COL_OFF  = 9431168;
    const size_t NEED     = 11991168;

    if (ws_size < NEED) return;       // never observed (ws ~268 MB)

    uint32_t* cursors   = (uint32_t*)ws;
    uint32_t* bucketbuf = (uint32_t*)(ws + BB_OFF);
    uint32_t* row_deg   = (uint32_t*)(ws + RD_OFF);
    float*    dinv      = (float*)(ws + DI_OFF);
    _Float16* wt        = (_Float16*)(ws + WT_OFF);
    _Float16* yw        = (_Float16*)(ws + YW_OFF);
    uint16_t* col       = (uint16_t*)(ws + COL_OFF);

    hipMemsetAsync(cursors, 0, 4096, stream);
    wcast_k  <<<64, 1024, 0, stream>>>(w, wt);
    sort_gemm<<<NBLK_E + NBLK_G, 1024, 0, stream>>>(ei, bucketbuf, cursors,
                                                    x, wt, yw);
    csr_only <<<NBLK_C, 1024, 0, stream>>>(bucketbuf, cursors,
                                           row_deg, dinv, col);
    spmm_out <<<N_NODES / 4, 256, 0, stream>>>(row_deg, dinv, col, yw, out);
}

// Round 6
// 129.540 us; speedup vs baseline: 3.1296x; 1.0127x over previous
//
#include <hip/hip_runtime.h>
#include <hip/hip_bf16.h>
#include <stdint.h>

// Problem constants (fixed by reference spec; dtypes f32/int32 verified over
// rounds 3-15 — bit-stable outputs; bounds-clamps retained as the safety net)
#define N_NODES   10000
#define D_FEAT    256
#define E_EDGES   320000
#define ROW_WORDS 313     // ceil(10000/32) bitmap words per row

// Bucket constants (r22: 625 buckets x 16 rows — all 16 waves used in D2,
// power-of-2 rows-per-bucket kills the s/RPB division in the sort).
#define NB     625        // buckets
#define RPB    16         // rows per bucket (power of 2)
#define B_CAP  1536       // entries per bucket; mean 1024, sigma ~32 (16 sigma)
#define NBLK_E 313        // sort blocks ((320000+1023)/1024)
#define NBLK_G 625        // gemm blocks (16 rows each), co-scheduled with sort
#define NBLK_C 625        // csr blocks (1:1 with buckets)
#define COLSTR 128        // fixed col entries per row (max deg ~100 << 128)

#define LDSTR 264         // f16 LDS row stride for gemm (256 + 8 pad)

typedef __attribute__((ext_vector_type(4))) float float4v;   // 4 x f32
typedef _Float16 half8  __attribute__((ext_vector_type(8))); // 8 x f16 (4 VGPR)
typedef _Float16 half4v __attribute__((ext_vector_type(4))); // 4 x f16

__device__ __forceinline__ float h2f_lo(uint32_t u) {
    union { uint32_t u; _Float16 h[2]; } v; v.u = u; return (float)v.h[0];
}
__device__ __forceinline__ float h2f_hi(uint32_t u) {
    union { uint32_t u; _Float16 h[2]; } v; v.u = u; return (float)v.h[1];
}

// ===========================================================================
// r22 PLAN — 4 dispatches, no memset:
//   D0 wcast_k  : wT cast (r12-proven body) + cursor zeroing (block 0)
//   D1 sort_gemm: [0,313) counting-sort fill (r17-proven scan, 625 bins)
//                 || [313,938) yw = f16(x @ W) MFMA (r10-proven body)
//   D2 csr_only : 625 bucket blocks: scan ~1024 entries -> 16-row LDS bitmap
//                 dedup -> 16 waves expand 16 rows -> col/deg/dinv
//   D3 spmm_out : r17-proven half-wave 16B gather -> d_out
// r21 post-mortem: gemm||sort overlap bought ~1.5 us only; kernels sum ~60 us
// against ~70 us fixed launch/graph overhead. This round removes one
// dispatch (memset) and the 6/16 idle-wave waste in D2. Inner loops verbatim.
// ===========================================================================

// ---------------------------------------------------------------------------
// D0: wt[n][k] = f16(W[k][n]); 64 blocks x 1024 thr, 4 W-rows per block.
//     Block 0 additionally zeroes the 1024 sort cursors (replaces memset).
// ---------------------------------------------------------------------------
__global__ void __launch_bounds__(1024)
wcast_k(const float* __restrict__ w, _Float16* __restrict__ wt,
        uint32_t* __restrict__ cursors) {
    __shared__ float st[1024];
    int t = threadIdx.x;
    if (blockIdx.x == 0) cursors[t] = 0u;          // 1024 u32, one block
    int kb = blockIdx.x * 4;
    int k = kb + (t >> 8), n = t & 255;
    st[(n << 2) | (t >> 8)] = w[(size_t)k * D_FEAT + n];
    __syncthreads();
    if (t < 256) {
        half4v o = { (_Float16)st[t * 4 + 0], (_Float16)st[t * 4 + 1],
                     (_Float16)st[t * 4 + 2], (_Float16)st[t * 4 + 3] };
        *(half4v*)&wt[(size_t)t * D_FEAT + kb] = o;
    }
}

// ---------------------------------------------------------------------------
// D1: blocks [0,313): counting-sorted bucket fill (1024-bin histogram, only
//     625 bins used; hierarchical shfl scan; coalesced run writes) —
//     r17-proven body, bucket fn now b = s>>4, lr = s&15 (lr 4 bits).
//     blocks [313,938): yw[16 rows] = f16(x @ W) MFMA — r10-proven verbatim.
// ---------------------------------------------------------------------------
__global__ void __launch_bounds__(1024)
sort_gemm(const int* __restrict__ ei, uint32_t* __restrict__ bucketbuf,
          uint32_t* __restrict__ cursors,
          const float* __restrict__ x, const _Float16* __restrict__ wt,
          _Float16* __restrict__ yw) {
    __shared__ __align__(16) uint8_t smraw[24640];
    int t = threadIdx.x;
    int wv = t >> 6, lane = t & 63;

    if (blockIdx.x >= NBLK_E) {        // ---- gemm blocks [313, 938) ----
        _Float16* a_lds = (_Float16*)smraw;            // 16*264 f16 = 8448 B
        int r0 = (blockIdx.x - NBLK_E) * 16;
        int row = t >> 6, c4 = (t & 63) * 4;           // 1024 thr = 16x64 f4
        float4v xv = *(const float4v*)(x + (size_t)(r0 + row) * D_FEAT + c4);
        half4v h = { (_Float16)xv[0], (_Float16)xv[1],
                     (_Float16)xv[2], (_Float16)xv[3] };
        *(half4v*)&a_lds[row * LDSTR + c4] = h;
        __syncthreads();
        int quad = lane >> 4, r = lane & 15;
        int ct = wv;                                   // 16 waves = 16 col tiles
        const _Float16* pb = wt + (size_t)(ct * 16 + r) * D_FEAT + quad * 8;
        float4v acc = {0.f, 0.f, 0.f, 0.f};
        #pragma unroll
        for (int kk = 0; kk < D_FEAT; kk += 32) {
            half8 a = *(const half8*)&a_lds[r * LDSTR + kk + quad * 8];
            half8 b = *(const half8*)(pb + kk);
            acc = __builtin_amdgcn_mfma_f32_16x16x32_f16(a, b, acc, 0, 0, 0);
        }
        int colg = ct * 16 + r;
        #pragma unroll
        for (int u = 0; u < 4; u++)
            yw[(size_t)(r0 + quad * 4 + u) * D_FEAT + colg] = (_Float16)acc[u];
        return;
    }

    // ---- sort blocks [0,313) — r17-proven body, arrays aliased in arena --
    uint32_t* hist   = (uint32_t*)(smraw);             //  4096 B
    uint32_t* lofs   = (uint32_t*)(smraw + 4096);      //  4096 B
    uint32_t* base_s = (uint32_t*)(smraw + 8192);      //  4096 B
    uint32_t* wsum   = (uint32_t*)(smraw + 12288);     //    64 B
    uint32_t* stage  = (uint32_t*)(smraw + 12352);     //  8192 B
    uint16_t* sbkt   = (uint16_t*)(smraw + 20544);     //  4096 B -> 24640

    hist[t] = 0;
    __syncthreads();
    int e = blockIdx.x * 1024 + t;
    int b0 = -1, b1 = -1; uint32_t ent0 = 0, ent1 = 0, s0 = 0, s1 = 0;
    if (e < E_EDGES) {
        int s = ei[e], d = ei[E_EDGES + e];
        if ((uint32_t)s < N_NODES && (uint32_t)d < N_NODES) {
            b0 = s >> 4; ent0 = ((uint32_t)(s & 15) << 14) | (uint32_t)d;
            b1 = d >> 4; ent1 = ((uint32_t)(d & 15) << 14) | (uint32_t)s;
            s0 = atomicAdd(&hist[b0], 1u);    // LDS atomics
            s1 = atomicAdd(&hist[b1], 1u);
        }
    }
    __syncthreads();
    // hierarchical inclusive scan: 64-wide shfl per wave, wave 0 combines
    uint32_t h = hist[t];
    uint32_t incl = h;
    #pragma unroll
    for (int off = 1; off < 64; off <<= 1) {
        uint32_t v = __shfl_up(incl, off, 64);
        if (lane >= off) incl += v;
    }
    if (lane == 63) wsum[wv] = incl;
    __syncthreads();
    if (wv == 0) {
        uint32_t s = (lane < 16) ? wsum[lane] : 0u;
        #pragma unroll
        for (int off = 1; off < 16; off <<= 1) {
            uint32_t v = __shfl_up(s, off, 64);
            if (lane >= off) s += v;
        }
        if (lane < 16) wsum[lane] = s;
    }
    __syncthreads();
    uint32_t wbase = wv ? wsum[wv - 1] : 0u;
    lofs[t] = incl + wbase;                          // inclusive scan value
    base_s[t] = h ? atomicAdd(&cursors[t], h) : 0u;
    __syncthreads();
    if (b0 >= 0) {                     // stage sorted by bucket
        uint32_t p0 = lofs[b0] - hist[b0] + s0;
        stage[p0] = ent0; sbkt[p0] = (uint16_t)b0;
        uint32_t p1 = lofs[b1] - hist[b1] + s1;
        stage[p1] = ent1; sbkt[p1] = (uint16_t)b1;
    }
    __syncthreads();
    uint32_t total = lofs[1023];
    for (uint32_t idx = t; idx < total; idx += 1024) {
        uint32_t b = sbkt[idx];
        uint32_t pos = base_s[b] + (idx - (lofs[b] - hist[b]));
        if (pos < B_CAP) bucketbuf[(size_t)b * B_CAP + pos] = stage[idx];
    }
}

// ---------------------------------------------------------------------------
// D2: 625 csr blocks (1:1 with buckets) — r16-proven body, 16-row buckets.
// Scan cnt[b] (~1024 <= 1536: 1-2 strided iterations), LDS bitmap dedup
// (20 KB), 16 waves expand 16 rows: popc -> deg/dinv, u16 col (fixed stride).
// ---------------------------------------------------------------------------
__global__ void __launch_bounds__(1024)
csr_only(const uint32_t* __restrict__ bucketbuf, const uint32_t* __restrict__ cursors,
         uint32_t* __restrict__ row_deg, float* __restrict__ dinv,
         uint16_t* __restrict__ col) {
    __shared__ __align__(16) uint32_t bm[RPB * ROW_WORDS];   // 20,032 B
    int t = threadIdx.x;
    int b = blockIdx.x;
    for (int i = t; i < RPB * ROW_WORDS; i += 1024) bm[i] = 0;
    __syncthreads();
    uint32_t cnt = min(cursors[b], (uint32_t)B_CAP);
    const uint32_t* bb = bucketbuf + (size_t)b * B_CAP;
    for (uint32_t i = t; i < cnt; i += 1024) {         // 1-2 iterations
        uint32_t ent = bb[i];
        uint32_t lr = ent >> 14, d = ent & 0x3FFFu;
        atomicOr(&bm[lr * ROW_WORDS + (d >> 5)], 1u << (d & 31));
    }
    __syncthreads();
    int wv = t >> 6, lane = t & 63;                    // 16 waves = 16 rows
    {
        int r = wv;
        int gi = b * RPB + r;
        uint32_t wb[5]; int tot = 0;
        #pragma unroll
        for (int k = 0; k < 5; k++) {
            int w = lane + 64 * k;
            uint32_t v = (w < ROW_WORDS) ? bm[r * ROW_WORDS + w] : 0u;
            wb[k] = v; tot += __popc(v);
        }
        int incl = tot;
        #pragma unroll
        for (int off = 1; off < 64; off <<= 1) {
            int v = __shfl_up(incl, off, 64);
            if (lane >= off) incl += v;
        }
        uint32_t total = (uint32_t)__shfl(incl, 63, 64);
        if (lane == 0) {
            row_deg[gi] = min(total, (uint32_t)COLSTR);
            dinv[gi]    = 1.0f / sqrtf((float)(total + 1u));  // +1 = the eye
        }
        uint32_t p = (uint32_t)(incl - tot);
        #pragma unroll
        for (int k = 0; k < 5; k++) {
            uint32_t bits = wb[k];
            uint32_t cbase = (uint32_t)(lane + 64 * k) << 5;
            while (bits) {
                if (p < COLSTR)
                    col[(size_t)gi * COLSTR + p] =
                        (uint16_t)(cbase + (uint32_t)__builtin_ctz(bits));
                p++;
                bits &= bits - 1;
            }
        }
    }
}

// ---------------------------------------------------------------------------
// D3: final gather straight into d_out (f32). Wave-per-row (10000 waves).
// r17-proven verbatim: half-wave per neighbor — 32 lanes x 16B cover one
// full 512B yw row; 16 neighbors/iter; next col block prefetched; tail
// folded branchlessly (index-clamp + weight-zero). yw is UNSCALED X@W.
// ---------------------------------------------------------------------------
__global__ void __launch_bounds__(256)
spmm_out(const uint32_t* __restrict__ row_deg, const float* __restrict__ dinv,
         const uint16_t* __restrict__ col, const _Float16* __restrict__ ywp,
         float* __restrict__ out) {
    const uint16_t* yw = (const uint16_t*)ywp;
    int wv = threadIdx.x >> 6, lane = threadIdx.x & 63;
    int half = lane >> 5, sl = lane & 31;
    int i = blockIdx.x * 4 + wv;
    uint32_t base = (uint32_t)i * COLSTR;
    uint32_t deg = min(row_deg[i], (uint32_t)COLSTR);
    float di = dinv[i];
    size_t ch = (size_t)sl * 8;                 // u16 elem offset within row
    float4v z = {0.f, 0.f, 0.f, 0.f};
    float4v accl[8], acch[8];
    #pragma unroll
    for (int k = 0; k < 8; k++) { accl[k] = z; acch[k] = z; }

    uint32_t hb = (uint32_t)(half << 3);
    uint4 cv = {0u, 0u, 0u, 0u};
    if (deg) cv = *(const uint4*)&col[base + hb];     // 8 idx, half-uniform

    for (uint32_t t = 0; t < deg; t += 16) {
        uint4 cvn = {0u, 0u, 0u, 0u};                 // prefetch next col blk
        uint32_t tn = t + 16;
        if (tn < deg) cvn = *(const uint4*)&col[base + tn + hb];
        uint32_t tb = t + hb;
        uint32_t jr[8];
        jr[0] = cv.x & 0xffffu; jr[1] = cv.x >> 16;
        jr[2] = cv.y & 0xffffu; jr[3] = cv.y >> 16;
        jr[4] = cv.z & 0xffffu; jr[5] = cv.z >> 16;
        jr[6] = cv.w & 0xffffu; jr[7] = cv.w >> 16;
        uint4 g[8]; float dk[8];
        #pragma unroll
        for (int k = 0; k < 8; k++) {                 // issue all 16 loads
            uint32_t j = min(jr[k], (uint32_t)(N_NODES - 1));  // stay in-bounds
            g[k]  = *(const uint4*)(yw + ((size_t)j << 8) + ch);
            dk[k] = dinv[j];
        }
        #pragma unroll
        for (int k = 0; k < 8; k++) {                 // convert + accumulate
            float d = (tb + (uint32_t)k < deg) ? dk[k] : 0.f;   // tail mask
            accl[k][0] += d * h2f_lo(g[k].x); accl[k][1] += d * h2f_hi(g[k].x);
            accl[k][2] += d * h2f_lo(g[k].y); accl[k][3] += d * h2f_hi(g[k].y);
            acch[k][0] += d * h2f_lo(g[k].z); acch[k][1] += d * h2f_hi(g[k].z);
            acch[k][2] += d * h2f_lo(g[k].w); acch[k][3] += d * h2f_hi(g[k].w);
        }
        cv = cvn;
    }

    if (half == 0) {                            // +I self term, once per row
        const uint4 gs = *(const uint4*)(yw + ((size_t)i << 8) + ch);
        accl[0][0] += di * h2f_lo(gs.x); accl[0][1] += di * h2f_hi(gs.x);
        accl[0][2] += di * h2f_lo(gs.y); accl[0][3] += di * h2f_hi(gs.y);
        acch[0][0] += di * h2f_lo(gs.z); acch[0][1] += di * h2f_hi(gs.z);
        acch[0][2] += di * h2f_lo(gs.w); acch[0][3] += di * h2f_hi(gs.w);
    }

    float4v lo = ((accl[0] + accl[1]) + (accl[2] + accl[3])) +
                 ((accl[4] + accl[5]) + (accl[6] + accl[7]));
    float4v hi = ((acch[0] + acch[1]) + (acch[2] + acch[3])) +
                 ((acch[4] + acch[5]) + (acch[6] + acch[7]));
    #pragma unroll
    for (int u = 0; u < 4; u++) {               // fold the two halves
        lo[u] += __shfl_xor(lo[u], 32, 64);
        hi[u] += __shfl_xor(hi[u], 32, 64);
    }
    float4v res;
    if (half) res = hi; else res = lo;
    // contiguous 1KB row store: lane l<32 -> feats sl*8..+3, l>=32 -> +4..+7
    float* op = out + (size_t)i * D_FEAT + (size_t)sl * 8 + (half ? 4 : 0);
    *(float4v*)op = di * res;
}

// ---------------------------------------------------------------------------
extern "C" void kernel_launch(void* const* d_in, const int* in_sizes, int n_in,
                              void* d_out, int out_size, void* d_ws, size_t ws_size,
                              hipStream_t stream) {
    const float* x  = (const float*)d_in[0];     // f32 [N, 256]
    const int*   ei = (const int*)d_in[1];       // int32 [2, E]
    const float* w  = (const float*)d_in[2];     // f32 [256, 256]
    float* out = (float*)d_out;                  // f32 [N, 256]
    uint8_t* ws = (uint8_t*)d_ws;

    // Layout (11.74 MB):
    //   cursors   @ 0          :      4,096  (1024 u32, zeroed by wcast_k)
    //   bucketbuf @ 4,096      :  3,840,000  (625 * 1536 u32)
    //   row_deg   @ 3,844,096  :     40,000
    //   dinv      @ 3,884,096  :     40,000
    //   wT (f16)  @ 3,924,096  :    131,072
    //   yw (f16)  @ 4,055,168  :  5,120,000  (X @ W, gather table)
    //   col (u16) @ 9,175,168  :  2,560,000  (10000 * 128 u16, fixed stride)
    const size_t BB_OFF   = 4096;
    const size_t RD_OFF   = 3844096;
    const size_t DI_OFF   = 3884096;
    const size_t WT_OFF   = 3924096;
    const size_t YW_OFF   = 4055168;
    const size_t COL_OFF  = 9175168;
    const size_t NEED     = 11735168;

    if (ws_size < NEED) return;       // never observed (ws ~268 MB)

    uint32_t* cursors   = (uint32_t*)ws;
    uint32_t* bucketbuf = (uint32_t*)(ws + BB_OFF);
    uint32_t* row_deg   = (uint32_t*)(ws + RD_OFF);
    float*    dinv      = (float*)(ws + DI_OFF);
    _Float16* wt        = (_Float16*)(ws + WT_OFF);
    _Float16* yw        = (_Float16*)(ws + YW_OFF);
    uint16_t* col       = (uint16_t*)(ws + COL_OFF);

    wcast_k  <<<64, 1024, 0, stream>>>(w, wt, cursors);
    sort_gemm<<<NBLK_E + NBLK_G, 1024, 0, stream>>>(ei, bucketbuf, cursors,
                                                    x, wt, yw);
    csr_only <<<NBLK_C, 1024, 0, stream>>>(bucketbuf, cursors,
                                           row_deg, dinv, col);
    spmm_out <<<N_NODES / 4, 256, 0, stream>>>(row_deg, dinv, col, yw, out);
}

// Round 7
// 129.380 us; speedup vs baseline: 3.1335x; 1.0012x over previous
//
#include <hip/hip_runtime.h>
#include <hip/hip_bf16.h>
#include <stdint.h>

// Problem constants (fixed by reference spec; dtypes f32/int32 verified over
// rounds 3-15 — bit-stable outputs; bounds-clamps retained as the safety net)
#define N_NODES   10000
#define D_FEAT    256
#define E_EDGES   320000
#define ROW_WORDS 313     // ceil(10000/32) bitmap words per row

// Bucket constants (r22-proven: 625 buckets x 16 rows)
#define NB     625        // buckets
#define RPB    16         // rows per bucket (power of 2)
#define B_CAP  1536       // entries per bucket; mean 1024, sigma ~32 (16 sigma)
#define NBLK_E 313        // sort blocks ((320000+1023)/1024)
#define NBLK_G 625        // gemm blocks (16 rows each), co-scheduled with sort
#define NBLK_C 625        // csr blocks (1:1 with buckets)
#define COLSTR 128        // fixed col entries per row (max deg ~100 << 128)

#define LDSTR 264         // f16 LDS row stride for gemm (256 + 8 pad)

typedef __attribute__((ext_vector_type(4))) float float4v;   // 4 x f32
typedef _Float16 half8  __attribute__((ext_vector_type(8))); // 8 x f16 (4 VGPR)
typedef _Float16 half4v __attribute__((ext_vector_type(4))); // 4 x f16

__device__ __forceinline__ float h2f_lo(uint32_t u) {
    union { uint32_t u; _Float16 h[2]; } v; v.u = u; return (float)v.h[0];
}
__device__ __forceinline__ float h2f_hi(uint32_t u) {
    union { uint32_t u; _Float16 h[2]; } v; v.u = u; return (float)v.h[1];
}

// ===========================================================================
// r23 PLAN — 4 dispatches; D3 gather is now FEATURE-SPLIT for XCD-L2 fit:
//   D0 wcast_k  : wT cast (r12-proven) + cursor zeroing (block 0)
//   D1 sort_gemm: [0,313) counting-sort fill || [313,938) yw = f16(x@W) MFMA
//   D2 csr_only : 625 bucket blocks -> 16-row LDS bitmap dedup -> col/deg/dinv
//   D3 spmm_half: 5000 blocks; wave = (row, feature-half). h = bid&1 so with
//                 round-robin bid%8 XCD mapping, each XCD touches only ONE
//                 2.44 MB half of yw -> fits 4 MiB XCD L2 (yw full = 4.88 MB
//                 thrashed it). 330 MB of gather reads move L3 -> L2.
//                 Wrong-mapping worst case: neutral, never incorrect.
// ===========================================================================

// ---------------------------------------------------------------------------
// D0: wt[n][k] = f16(W[k][n]); 64 blocks x 1024 thr, 4 W-rows per block.
//     Block 0 additionally zeroes the 1024 sort cursors (replaces memset).
// ---------------------------------------------------------------------------
__global__ void __launch_bounds__(1024)
wcast_k(const float* __restrict__ w, _Float16* __restrict__ wt,
        uint32_t* __restrict__ cursors) {
    __shared__ float st[1024];
    int t = threadIdx.x;
    if (blockIdx.x == 0) cursors[t] = 0u;          // 1024 u32, one block
    int kb = blockIdx.x * 4;
    int k = kb + (t >> 8), n = t & 255;
    st[(n << 2) | (t >> 8)] = w[(size_t)k * D_FEAT + n];
    __syncthreads();
    if (t < 256) {
        half4v o = { (_Float16)st[t * 4 + 0], (_Float16)st[t * 4 + 1],
                     (_Float16)st[t * 4 + 2], (_Float16)st[t * 4 + 3] };
        *(half4v*)&wt[(size_t)t * D_FEAT + kb] = o;
    }
}

// ---------------------------------------------------------------------------
// D1: blocks [0,313): counting-sorted bucket fill (1024-bin histogram, 625
//     bins used; hierarchical shfl scan; coalesced run writes) — r22-proven.
//     blocks [313,938): yw[16 rows] = f16(x @ W) MFMA — r10-proven verbatim.
// ---------------------------------------------------------------------------
__global__ void __launch_bounds__(1024)
sort_gemm(const int* __restrict__ ei, uint32_t* __restrict__ bucketbuf,
          uint32_t* __restrict__ cursors,
          const float* __restrict__ x, const _Float16* __restrict__ wt,
          _Float16* __restrict__ yw) {
    __shared__ __align__(16) uint8_t smraw[24640];
    int t = threadIdx.x;
    int wv = t >> 6, lane = t & 63;

    if (blockIdx.x >= NBLK_E) {        // ---- gemm blocks [313, 938) ----
        _Float16* a_lds = (_Float16*)smraw;            // 16*264 f16 = 8448 B
        int r0 = (blockIdx.x - NBLK_E) * 16;
        int row = t >> 6, c4 = (t & 63) * 4;           // 1024 thr = 16x64 f4
        float4v xv = *(const float4v*)(x + (size_t)(r0 + row) * D_FEAT + c4);
        half4v h = { (_Float16)xv[0], (_Float16)xv[1],
                     (_Float16)xv[2], (_Float16)xv[3] };
        *(half4v*)&a_lds[row * LDSTR + c4] = h;
        __syncthreads();
        int quad = lane >> 4, r = lane & 15;
        int ct = wv;                                   // 16 waves = 16 col tiles
        const _Float16* pb = wt + (size_t)(ct * 16 + r) * D_FEAT + quad * 8;
        float4v acc = {0.f, 0.f, 0.f, 0.f};
        #pragma unroll
        for (int kk = 0; kk < D_FEAT; kk += 32) {
            half8 a = *(const half8*)&a_lds[r * LDSTR + kk + quad * 8];
            half8 b = *(const half8*)(pb + kk);
            acc = __builtin_amdgcn_mfma_f32_16x16x32_f16(a, b, acc, 0, 0, 0);
        }
        int colg = ct * 16 + r;
        #pragma unroll
        for (int u = 0; u < 4; u++)
            yw[(size_t)(r0 + quad * 4 + u) * D_FEAT + colg] = (_Float16)acc[u];
        return;
    }

    // ---- sort blocks [0,313) — r22-proven body, arrays aliased in arena --
    uint32_t* hist   = (uint32_t*)(smraw);             //  4096 B
    uint32_t* lofs   = (uint32_t*)(smraw + 4096);      //  4096 B
    uint32_t* base_s = (uint32_t*)(smraw + 8192);      //  4096 B
    uint32_t* wsum   = (uint32_t*)(smraw + 12288);     //    64 B
    uint32_t* stage  = (uint32_t*)(smraw + 12352);     //  8192 B
    uint16_t* sbkt   = (uint16_t*)(smraw + 20544);     //  4096 B -> 24640

    hist[t] = 0;
    __syncthreads();
    int e = blockIdx.x * 1024 + t;
    int b0 = -1, b1 = -1; uint32_t ent0 = 0, ent1 = 0, s0 = 0, s1 = 0;
    if (e < E_EDGES) {
        int s = ei[e], d = ei[E_EDGES + e];
        if ((uint32_t)s < N_NODES && (uint32_t)d < N_NODES) {
            b0 = s >> 4; ent0 = ((uint32_t)(s & 15) << 14) | (uint32_t)d;
            b1 = d >> 4; ent1 = ((uint32_t)(d & 15) << 14) | (uint32_t)s;
            s0 = atomicAdd(&hist[b0], 1u);    // LDS atomics
            s1 = atomicAdd(&hist[b1], 1u);
        }
    }
    __syncthreads();
    // hierarchical inclusive scan: 64-wide shfl per wave, wave 0 combines
    uint32_t h = hist[t];
    uint32_t incl = h;
    #pragma unroll
    for (int off = 1; off < 64; off <<= 1) {
        uint32_t v = __shfl_up(incl, off, 64);
        if (lane >= off) incl += v;
    }
    if (lane == 63) wsum[wv] = incl;
    __syncthreads();
    if (wv == 0) {
        uint32_t s = (lane < 16) ? wsum[lane] : 0u;
        #pragma unroll
        for (int off = 1; off < 16; off <<= 1) {
            uint32_t v = __shfl_up(s, off, 64);
            if (lane >= off) s += v;
        }
        if (lane < 16) wsum[lane] = s;
    }
    __syncthreads();
    uint32_t wbase = wv ? wsum[wv - 1] : 0u;
    lofs[t] = incl + wbase;                          // inclusive scan value
    base_s[t] = h ? atomicAdd(&cursors[t], h) : 0u;
    __syncthreads();
    if (b0 >= 0) {                     // stage sorted by bucket
        uint32_t p0 = lofs[b0] - hist[b0] + s0;
        stage[p0] = ent0; sbkt[p0] = (uint16_t)b0;
        uint32_t p1 = lofs[b1] - hist[b1] + s1;
        stage[p1] = ent1; sbkt[p1] = (uint16_t)b1;
    }
    __syncthreads();
    uint32_t total = lofs[1023];
    for (uint32_t idx = t; idx < total; idx += 1024) {
        uint32_t b = sbkt[idx];
        uint32_t pos = base_s[b] + (idx - (lofs[b] - hist[b]));
        if (pos < B_CAP) bucketbuf[(size_t)b * B_CAP + pos] = stage[idx];
    }
}

// ---------------------------------------------------------------------------
// D2: 625 csr blocks (1:1 with buckets) — r22-proven body; uint4 LDS zero.
// ---------------------------------------------------------------------------
__global__ void __launch_bounds__(1024)
csr_only(const uint32_t* __restrict__ bucketbuf, const uint32_t* __restrict__ cursors,
         uint32_t* __restrict__ row_deg, float* __restrict__ dinv,
         uint16_t* __restrict__ col) {
    __shared__ __align__(16) uint32_t bm[RPB * ROW_WORDS];   // 20,032 B
    int t = threadIdx.x;
    int b = blockIdx.x;
    {   // vectorized zero: 5008 words = 1252 uint4
        uint4 zz = {0u, 0u, 0u, 0u};
        uint4* bm4 = (uint4*)bm;
        for (int i = t; i < (RPB * ROW_WORDS) / 4; i += 1024) bm4[i] = zz;
    }
    __syncthreads();
    uint32_t cnt = min(cursors[b], (uint32_t)B_CAP);
    const uint32_t* bb = bucketbuf + (size_t)b * B_CAP;
    for (uint32_t i = t; i < cnt; i += 1024) {         // 1-2 iterations
        uint32_t ent = bb[i];
        uint32_t lr = ent >> 14, d = ent & 0x3FFFu;
        atomicOr(&bm[lr * ROW_WORDS + (d >> 5)], 1u << (d & 31));
    }
    __syncthreads();
    int wv = t >> 6, lane = t & 63;                    // 16 waves = 16 rows
    {
        int r = wv;
        int gi = b * RPB + r;
        uint32_t wb[5]; int tot = 0;
        #pragma unroll
        for (int k = 0; k < 5; k++) {
            int w = lane + 64 * k;
            uint32_t v = (w < ROW_WORDS) ? bm[r * ROW_WORDS + w] : 0u;
            wb[k] = v; tot += __popc(v);
        }
        int incl = tot;
        #pragma unroll
        for (int off = 1; off < 64; off <<= 1) {
            int v = __shfl_up(incl, off, 64);
            if (lane >= off) incl += v;
        }
        uint32_t total = (uint32_t)__shfl(incl, 63, 64);
        if (lane == 0) {
            row_deg[gi] = min(total, (uint32_t)COLSTR);
            dinv[gi]    = 1.0f / sqrtf((float)(total + 1u));  // +1 = the eye
        }
        uint32_t p = (uint32_t)(incl - tot);
        #pragma unroll
        for (int k = 0; k < 5; k++) {
            uint32_t bits = wb[k];
            uint32_t cbase = (uint32_t)(lane + 64 * k) << 5;
            while (bits) {
                if (p < COLSTR)
                    col[(size_t)gi * COLSTR + p] =
                        (uint16_t)(cbase + (uint32_t)__builtin_ctz(bits));
                p++;
                bits &= bits - 1;
            }
        }
    }
}

// ---------------------------------------------------------------------------
// D3: feature-split gather. 5000 blocks x 256 thr; wave = (row, half-feat).
//   h = bid & 1  (feature half: u16 elems [h*128, h*128+128))
//   i = (bid >> 1) * 4 + wv
// With round-robin bid%8 XCD mapping, even XCDs read only yw[:,0:128]
// (2.44 MB) -> per-XCD gather footprint fits 4 MiB L2. Inner loop keeps the
// r17-proven skeleton: half-wave (hw) neighbor streams, 16 neighbors/iter,
// col prefetch, branchless tail (index-clamp + weight-zero), self term on
// hw==0, shfl_xor(32) fold. Loads are uint2 (8 B/lane x 32 lanes = 256 B =
// half yw row per neighbor). yw is UNSCALED X@W (out = S.(X.W)).
// ---------------------------------------------------------------------------
__global__ void __launch_bounds__(256)
spmm_half(const uint32_t* __restrict__ row_deg, const float* __restrict__ dinv,
          const uint16_t* __restrict__ col, const _Float16* __restrict__ ywp,
          float* __restrict__ out) {
    const uint16_t* yw = (const uint16_t*)ywp;
    int bid = blockIdx.x;
    int h = bid & 1;                            // feature half
    int wv = threadIdx.x >> 6, lane = threadIdx.x & 63;
    int hw = lane >> 5, sl = lane & 31;         // neighbor-stream half-wave
    int i = (bid >> 1) * 4 + wv;
    uint32_t base = (uint32_t)i * COLSTR;
    uint32_t deg = min(row_deg[i], (uint32_t)COLSTR);
    float di = dinv[i];
    size_t ch = (size_t)(h << 7) + (size_t)sl * 4;   // u16 elem offset in row
    float4v z = {0.f, 0.f, 0.f, 0.f};
    float4v a[8];
    #pragma unroll
    for (int k = 0; k < 8; k++) a[k] = z;

    uint32_t hb = (uint32_t)(hw << 3);
    uint4 cv = {0u, 0u, 0u, 0u};
    if (deg) cv = *(const uint4*)&col[base + hb];     // 8 idx, halfwave-uniform

    for (uint32_t t = 0; t < deg; t += 16) {
        uint4 cvn = {0u, 0u, 0u, 0u};                 // prefetch next col blk
        uint32_t tn = t + 16;
        if (tn < deg) cvn = *(const uint4*)&col[base + tn + hb];
        uint32_t tb = t + hb;
        uint32_t jr[8];
        jr[0] = cv.x & 0xffffu; jr[1] = cv.x >> 16;
        jr[2] = cv.y & 0xffffu; jr[3] = cv.y >> 16;
        jr[4] = cv.z & 0xffffu; jr[5] = cv.z >> 16;
        jr[6] = cv.w & 0xffffu; jr[7] = cv.w >> 16;
        uint2 g[8]; float dk[8];
        #pragma unroll
        for (int k = 0; k < 8; k++) {                 // issue all 16 loads
            uint32_t j = min(jr[k], (uint32_t)(N_NODES - 1));  // stay in-bounds
            g[k]  = *(const uint2*)(yw + ((size_t)j << 8) + ch);
            dk[k] = dinv[j];
        }
        #pragma unroll
        for (int k = 0; k < 8; k++) {                 // convert + accumulate
            float d = (tb + (uint32_t)k < deg) ? dk[k] : 0.f;   // tail mask
            a[k][0] += d * h2f_lo(g[k].x); a[k][1] += d * h2f_hi(g[k].x);
            a[k][2] += d * h2f_lo(g[k].y); a[k][3] += d * h2f_hi(g[k].y);
        }
        cv = cvn;
    }

    if (hw == 0) {                              // +I self term, once per row
        const uint2 gs = *(const uint2*)(yw + ((size_t)i << 8) + ch);
        a[0][0] += di * h2f_lo(gs.x); a[0][1] += di * h2f_hi(gs.x);
        a[0][2] += di * h2f_lo(gs.y); a[0][3] += di * h2f_hi(gs.y);
    }

    float4v acc = ((a[0] + a[1]) + (a[2] + a[3])) + ((a[4] + a[5]) + (a[6] + a[7]));
    #pragma unroll
    for (int u = 0; u < 4; u++)                 // fold the two hw streams
        acc[u] += __shfl_xor(acc[u], 32, 64);
    if (hw == 0) {                              // 32 lanes x 16 B = 512 B
        float* op = out + (size_t)i * D_FEAT + (h << 7) + sl * 4;
        *(float4v*)op = di * acc;
    }
}

// ---------------------------------------------------------------------------
extern "C" void kernel_launch(void* const* d_in, const int* in_sizes, int n_in,
                              void* d_out, int out_size, void* d_ws, size_t ws_size,
                              hipStream_t stream) {
    const float* x  = (const float*)d_in[0];     // f32 [N, 256]
    const int*   ei = (const int*)d_in[1];       // int32 [2, E]
    const float* w  = (const float*)d_in[2];     // f32 [256, 256]
    float* out = (float*)d_out;                  // f32 [N, 256]
    uint8_t* ws = (uint8_t*)d_ws;

    // Layout (11.74 MB):
    //   cursors   @ 0          :      4,096  (1024 u32, zeroed by wcast_k)
    //   bucketbuf @ 4,096      :  3,840,000  (625 * 1536 u32)
    //   row_deg   @ 3,844,096  :     40,000
    //   dinv      @ 3,884,096  :     40,000
    //   wT (f16)  @ 3,924,096  :    131,072
    //   yw (f16)  @ 4,055,168  :  5,120,000  (X @ W, gather table)
    //   col (u16) @ 9,175,168  :  2,560,000  (10000 * 128 u16, fixed stride)
    const size_t BB_OFF   = 4096;
    const size_t RD_OFF   = 3844096;
    const size_t DI_OFF   = 3884096;
    const size_t WT_OFF   = 3924096;
    const size_t YW_OFF   = 4055168;
    const size_t COL_OFF  = 9175168;
    const size_t NEED     = 11735168;

    if (ws_size < NEED) return;       // never observed (ws ~268 MB)

    uint32_t* cursors   = (uint32_t*)ws;
    uint32_t* bucketbuf = (uint32_t*)(ws + BB_OFF);
    uint32_t* row_deg   = (uint32_t*)(ws + RD_OFF);
    float*    dinv      = (float*)(ws + DI_OFF);
    _Float16* wt        = (_Float16*)(ws + WT_OFF);
    _Float16* yw        = (_Float16*)(ws + YW_OFF);
    uint16_t* col       = (uint16_t*)(ws + COL_OFF);

    wcast_k  <<<64, 1024, 0, stream>>>(w, wt, cursors);
    sort_gemm<<<NBLK_E + NBLK_G, 1024, 0, stream>>>(ei, bucketbuf, cursors,
                                                    x, wt, yw);
    csr_only <<<NBLK_C, 1024, 0, stream>>>(bucketbuf, cursors,
                                           row_deg, dinv, col);
    spmm_half<<<N_NODES / 2, 256, 0, stream>>>(row_deg, dinv, col, yw, out);
}